// Round 1
// baseline (979.257 us; speedup 1.0000x reference)
//
#include <hip/hip_runtime.h>
#include <hip/hip_bf16.h>

#define HGT 1024
#define WID 1024
#define DT_C 0.1f
#define ALPHA_C 0.05f
#define VX_C 0.1f

// One simulation step: read u (HGT*WID floats), write one frame (3 planes).
// r-plane of the output frame == u_new, so it doubles as the next step's input.
__global__ __launch_bounds__(256) void step_kernel(const float* __restrict__ u_in,
                                                   float* __restrict__ frame_out) {
    int t = blockIdx.x * blockDim.x + threadIdx.x;   // 0 .. HGT*WID/4 - 1
    int vx = t & (WID / 4 - 1);                      // float4 index in row
    int y  = t >> 8;                                 // t / (WID/4)
    int x0 = vx << 2;

    const float4* rowc = (const float4*)(u_in + (size_t)y * WID);
    const float4* rowu = (const float4*)(u_in + (size_t)((y - 1) & (HGT - 1)) * WID);
    const float4* rowd = (const float4*)(u_in + (size_t)((y + 1) & (HGT - 1)) * WID);

    float4 c  = rowc[vx];
    float4 up = rowu[vx];
    float4 dn = rowd[vx];
    float left  = u_in[(size_t)y * WID + ((x0 - 1) & (WID - 1))];
    float right = u_in[(size_t)y * WID + ((x0 + 4) & (WID - 1))];

    float cl[6]  = {left, c.x, c.y, c.z, c.w, right};
    float upv[4] = {up.x, up.y, up.z, up.w};
    float dnv[4] = {dn.x, dn.y, dn.z, dn.w};

    float un[4];
#pragma unroll
    for (int i = 0; i < 4; i++) {
        float cc = cl[i + 1], ll = cl[i], rr = cl[i + 2];
        float lap  = ll + rr + upv[i] + dnv[i] - 4.0f * cc;
        float dudx = cc - ll;
        float v = cc + DT_C * (ALPHA_C * lap - VX_C * dudx);   // V_Y == 0
        un[i] = fminf(fmaxf(v, 0.0f), 1.0f);
    }

    float4 rv = make_float4(un[0], un[1], un[2], un[3]);
    float4 gv = make_float4(0.5f * un[0], 0.5f * un[1], 0.5f * un[2], 0.5f * un[3]);
    float4 bv = make_float4(1.0f - un[0], 1.0f - un[1], 1.0f - un[2], 1.0f - un[3]);

    size_t row_off = (size_t)y * WID;
    ((float4*)(frame_out + 0 * (size_t)HGT * WID + row_off))[vx] = rv;
    ((float4*)(frame_out + 1 * (size_t)HGT * WID + row_off))[vx] = gv;
    ((float4*)(frame_out + 2 * (size_t)HGT * WID + row_off))[vx] = bv;
}

extern "C" void kernel_launch(void* const* d_in, const int* in_sizes, int n_in,
                              void* d_out, int out_size, void* d_ws, size_t ws_size,
                              hipStream_t stream) {
    const float* u0 = (const float*)d_in[0];
    float* out = (float*)d_out;

    const size_t plane = (size_t)HGT * WID;       // 1 Mi elements
    const size_t frame_elems = 3 * plane;
    int T = (int)((size_t)out_size / frame_elems); // = n_frames (64)

    const int threads = 256;
    const int blocks = (int)(plane / 4 / threads); // 1024 blocks

    const float* u = u0;
    for (int t = 0; t < T; t++) {
        float* frame = out + (size_t)t * frame_elems;
        step_kernel<<<blocks, threads, 0, stream>>>(u, frame);
        u = frame;  // r-plane of frame t == u state for step t+1
    }
}